// Round 13
// baseline (201.184 us; speedup 1.0000x reference)
//
#include <hip/hip_runtime.h>
#include <hip/hip_bf16.h>
#include <stdint.h>

typedef __attribute__((ext_vector_type(8))) short short8;
typedef __attribute__((ext_vector_type(4))) float f32x4;
typedef __attribute__((ext_vector_type(4))) int int4v;

__device__ __forceinline__ unsigned short f2bf(float f) {
    union { float f; uint32_t u; } v; v.f = f;
    return (unsigned short)((v.u + 0x7FFFu + ((v.u >> 16) & 1u)) >> 16);
}

// Build W directly in MFMA-FRAGMENT order:
//   Wfrag[((ct*6 + c)*64 + lane)*8 + e] = bf16( W[ct*16 + (lane&15)][c*32 + (lane>>4)*8 + e] )
// where W[j][k] = kernel[cayley[inv[k>>4], j>>4]][j&15][k&15].
// Each wave's ds_read_b128 for (ct,c) is lane-linear 16B -> conflict-free (R8/R9: 0 conflicts).
__global__ void build_w_kernel(const float* __restrict__ kern,
                               const int* __restrict__ cayley,
                               const int* __restrict__ inv,
                               unsigned short* __restrict__ Wfrag) {
    int i = blockIdx.x * blockDim.x + threadIdx.x;   // i = ((ct*6+c)*64 + lane)*8 + e
    if (i >= 192 * 192) return;
    int e    = i & 7;
    int lane = (i >> 3) & 63;
    int fc   = i >> 9;            // ct*6 + c
    int ct   = fc / 6, c = fc - ct * 6;
    int j = ct * 16 + (lane & 15);
    int k = c * 32 + (lane >> 4) * 8 + e;
    int h = j >> 4, oc = j & 15;
    int g = k >> 4, ic = k & 15;
    int cidx = cayley[inv[g] * 12 + h];
    Wfrag[i] = f2bf(kern[cidx * 256 + oc * 16 + ic]);
}

// out[n][j] = sum_k x[n][k] * W[j][k] + bias[j]
// R11 (182.5us, best): plain stores beat NT (L2 write-combining). Residual gap
// vs ~120us roofline theorized as store-drain serialization: strip N+1's loads
// queue behind strip N's 12 stores (in-order vmcnt), so the cvt waitcnt also
// waits store acks. A/B vs R11, SINGLE variable: 1024-thr blocks (16 waves) x
// 512 blocks = 2 blocks/CU = 32 waves/CU (double R11's TLP) to overlap drain.
// (1024,4) => 64-VGPR cap; R10 compiled this body to 48 VGPR, zero spills.
// Keep: two-batch staging, sched_barrier(0) loop bottom, fragment-order LDS W,
// swapped MFMA, plain dwordx4 stores.
__global__ __launch_bounds__(1024, 4) void gemm_kernel(
    const float* __restrict__ x,
    const unsigned short* __restrict__ Wfrag,
    const float* __restrict__ bias,
    float* __restrict__ out, int nstrips, int spw) {
  __shared__ unsigned char lds[192 * 192 * 2];   // 73728 B, fragment order
  const int tid  = threadIdx.x;
  const int lane = tid & 63;
  const int wid  = tid >> 6;
  const int l15  = lane & 15;
  const int lhi  = lane >> 4;

  // Stage W fragments into LDS (linear copy; 4608 int4 / 1024 thr).
  {
    const int4v* src = (const int4v*)Wfrag;
    int4v* dst = (int4v*)lds;
    #pragma unroll
    for (int t = 0; t < 5; ++t) {
      int idx = tid + t * 1024;
      if (idx < 4608) dst[idx] = src[idx];
    }
  }
  __syncthreads();

  const int gw = blockIdx.x * 16 + wid;    // global wave id
  int strip = gw * spw;
  const int send = min(strip + spw, nstrips);

  // bias for this lane's 4 output features (j = ct*16 + lhi*4 + r)
  const f32x4 bias4 = *(const f32x4*)(bias + lhi * 4);
  // LDS fragment base for this lane: frag (ct,c) at lane*16 + (ct*6+c)*1024
  const unsigned char* wbase = lds + lane * 16;

  while (strip < send) {
    short8 abf[6];
    {
      const float* xr = x + (size_t)(strip * 16 + l15) * 192 + lhi * 8;
      // Batch A: lo halves (k = c*32 + lhi*8 + 0..3)
      f32x4 fa[6];
      #pragma unroll
      for (int c = 0; c < 6; ++c) fa[c] = *(const f32x4*)(xr + c * 32);
      #pragma unroll
      for (int c = 0; c < 6; ++c)
        #pragma unroll
        for (int e = 0; e < 4; ++e) abf[c][e] = (short)f2bf(fa[c][e]);
      // Batch B: hi halves (k = c*32 + lhi*8 + 4..7)
      f32x4 fb[6];
      #pragma unroll
      for (int c = 0; c < 6; ++c) fb[c] = *(const f32x4*)(xr + c * 32 + 4);
      #pragma unroll
      for (int c = 0; c < 6; ++c)
        #pragma unroll
        for (int e = 0; e < 4; ++e) abf[c][e + 4] = (short)f2bf(fb[c][e]);
    }

    float* obase = out + (size_t)(strip * 16 + l15) * 192 + lhi * 4;
    #pragma unroll
    for (int ct = 0; ct < 12; ++ct) {
      f32x4 acc = {0.f, 0.f, 0.f, 0.f};
      #pragma unroll
      for (int c = 0; c < 6; ++c) {
        short8 w = *(const short8*)(wbase + (ct * 6 + c) * 1024);
        acc = __builtin_amdgcn_mfma_f32_16x16x32_bf16(w, abf[c], acc, 0, 0, 0);
      }
      f32x4 res = {acc[0] + bias4[0], acc[1] + bias4[1],
                   acc[2] + bias4[2], acc[3] + bias4[3]};
      *(f32x4*)(obase + ct * 16) = res;   // plain store: L2 write-combines sectors
    }
    ++strip;
    // Fence: forbid hoisting next strip's loads above this point (spill source).
    __builtin_amdgcn_sched_barrier(0);
  }
}

extern "C" void kernel_launch(void* const* d_in, const int* in_sizes, int n_in,
                              void* d_out, int out_size, void* d_ws, size_t ws_size,
                              hipStream_t stream) {
    const float* x      = (const float*)d_in[0];
    const float* kern   = (const float*)d_in[1];
    const float* bias   = (const float*)d_in[2];
    const int*   cayley = (const int*)d_in[3];
    const int*   inv    = (const int*)d_in[4];
    float* out = (float*)d_out;
    unsigned short* Wfrag = (unsigned short*)d_ws;   // 73728 bytes

    const int nrows = in_sizes[0] / 192;
    const int nstrips = nrows / 16;                  // 32768

    build_w_kernel<<<(192 * 192 + 255) / 256, 256, 0, stream>>>(kern, cayley, inv, Wfrag);

    const int nblocks = 512;                         // persistent, 2 blocks/CU (32 waves/CU)
    const int nwaves  = nblocks * 16;                // 8192 waves
    const int spw     = (nstrips + nwaves - 1) / nwaves;   // = 4
    gemm_kernel<<<nblocks, 1024, 0, stream>>>(x, Wfrag, bias, out, nstrips, spw);
}

// Round 14
// 182.215 us; speedup vs baseline: 1.1041x; 1.1041x over previous
//
#include <hip/hip_runtime.h>
#include <hip/hip_bf16.h>
#include <stdint.h>

typedef __attribute__((ext_vector_type(8))) short short8;
typedef __attribute__((ext_vector_type(4))) float f32x4;
typedef __attribute__((ext_vector_type(4))) int int4v;

__device__ __forceinline__ unsigned short f2bf(float f) {
    union { float f; uint32_t u; } v; v.f = f;
    return (unsigned short)((v.u + 0x7FFFu + ((v.u >> 16) & 1u)) >> 16);
}

// Build W in MFMA-FRAGMENT order with the LINE-COALESCED k-map:
//   lane (l15,lhi), elem e holds k = c*32 + (e<4 ? lhi*4+e : 16+lhi*4+(e-4))
// so that the x-loads for elems 0..3 of a wave cover one FULL 64B line per row
// (lanes lhi=0..3 contiguous 16B chunks) and elems 4..7 the next line.
// The (lane,e)->k permutation is shared by A(x) and B(W) so it cancels in MFMA.
//   Wfrag[((ct*6 + c)*64 + lane)*8 + e] = bf16( W[ct*16 + (lane&15)][k] )
// where W[j][k] = kernel[cayley[inv[k>>4], j>>4]][j&15][k&15].
__global__ void build_w_kernel(const float* __restrict__ kern,
                               const int* __restrict__ cayley,
                               const int* __restrict__ inv,
                               unsigned short* __restrict__ Wfrag) {
    int i = blockIdx.x * blockDim.x + threadIdx.x;   // i = ((ct*6+c)*64 + lane)*8 + e
    if (i >= 192 * 192) return;
    int e    = i & 7;
    int lane = (i >> 3) & 63;
    int fc   = i >> 9;            // ct*6 + c
    int ct   = fc / 6, c = fc - ct * 6;
    int j = ct * 16 + (lane & 15);
    int lhi = lane >> 4;
    int k = c * 32 + ((e < 4) ? (lhi * 4 + e) : (16 + lhi * 4 + (e - 4)));
    int h = j >> 4, oc = j & 15;
    int g = k >> 4, ic = k & 15;
    int cidx = cayley[inv[g] * 12 + h];
    Wfrag[i] = f2bf(kern[cidx * 256 + oc * 16 + ic]);
}

// out[n][j] = sum_k x[n][k] * W[j][k] + bias[j]
// R12 post-mortem: perf flat vs occupancy (11..43%) AND bytes -> per-CU vmem
// line-transaction (TA) throughput theory. Stores already minimal (each instr =
// 16 fully-covered 64B lines). OLD loads: 32 half-covered lines/instr, touched
// twice (576 transactions/strip). NEW line-coalesced k-map (see build_w): each
// load instr = 16 fully-covered lines; 384 transactions/strip total = minimal.
// Config otherwise identical to R11 (182.5us best): 512-thr persistent blocks,
// (512,4) => 64-VGPR cap (compiled 60, zero spills), fragment-order LDS W
// (0 bank conflicts), two-batch staging, sched_barrier(0) at loop bottom,
// swapped MFMA, plain dwordx4 stores (L2 write-combining; NT was -20us).
__global__ __launch_bounds__(512, 4) void gemm_kernel(
    const float* __restrict__ x,
    const unsigned short* __restrict__ Wfrag,
    const float* __restrict__ bias,
    float* __restrict__ out, int nstrips, int spw) {
  __shared__ unsigned char lds[192 * 192 * 2];   // 73728 B, fragment order
  const int tid  = threadIdx.x;
  const int lane = tid & 63;
  const int wid  = tid >> 6;
  const int l15  = lane & 15;
  const int lhi  = lane >> 4;

  // Stage W fragments into LDS (pure linear copy, 73728 B / 512 thr = 9 x int4).
  {
    const int4v* src = (const int4v*)Wfrag;
    int4v* dst = (int4v*)lds;
    #pragma unroll
    for (int t = 0; t < 9; ++t) dst[tid + t * 512] = src[tid + t * 512];
  }
  __syncthreads();

  const int gw = blockIdx.x * 8 + wid;    // global wave id
  int strip = gw * spw;
  const int send = min(strip + spw, nstrips);

  // bias for this lane's 4 output features (j = ct*16 + lhi*4 + r)
  const f32x4 bias4 = *(const f32x4*)(bias + lhi * 4);
  // LDS fragment base for this lane: frag (ct,c) at lane*16 + (ct*6+c)*1024
  const unsigned char* wbase = lds + lane * 16;

  while (strip < send) {
    short8 abf[6];
    {
      // Lane's 16B chunk base: row l15, float offset lhi*4 within each 128B c-window.
      const float* xr = x + (size_t)(strip * 16 + l15) * 192 + lhi * 4;
      // Batch A: first 64B line of each c-window (k = c*32 + lhi*4 + 0..3)
      f32x4 fa[6];
      #pragma unroll
      for (int c = 0; c < 6; ++c) fa[c] = *(const f32x4*)(xr + c * 32);
      #pragma unroll
      for (int c = 0; c < 6; ++c)
        #pragma unroll
        for (int e = 0; e < 4; ++e) abf[c][e] = (short)f2bf(fa[c][e]);
      // Batch B: second 64B line (k = c*32 + 16 + lhi*4 + 0..3)
      f32x4 fb[6];
      #pragma unroll
      for (int c = 0; c < 6; ++c) fb[c] = *(const f32x4*)(xr + c * 32 + 16);
      #pragma unroll
      for (int c = 0; c < 6; ++c)
        #pragma unroll
        for (int e = 0; e < 4; ++e) abf[c][e + 4] = (short)f2bf(fb[c][e]);
    }

    float* obase = out + (size_t)(strip * 16 + l15) * 192 + lhi * 4;
    #pragma unroll
    for (int ct = 0; ct < 12; ++ct) {
      f32x4 acc = {0.f, 0.f, 0.f, 0.f};
      #pragma unroll
      for (int c = 0; c < 6; ++c) {
        short8 w = *(const short8*)(wbase + (ct * 6 + c) * 1024);
        acc = __builtin_amdgcn_mfma_f32_16x16x32_bf16(w, abf[c], acc, 0, 0, 0);
      }
      f32x4 res = {acc[0] + bias4[0], acc[1] + bias4[1],
                   acc[2] + bias4[2], acc[3] + bias4[3]};
      *(f32x4*)(obase + ct * 16) = res;   // plain store: L2 write-combines sectors
    }
    ++strip;
    // Fence: forbid hoisting next strip's loads above this point (spill source).
    __builtin_amdgcn_sched_barrier(0);
  }
}

extern "C" void kernel_launch(void* const* d_in, const int* in_sizes, int n_in,
                              void* d_out, int out_size, void* d_ws, size_t ws_size,
                              hipStream_t stream) {
    const float* x      = (const float*)d_in[0];
    const float* kern   = (const float*)d_in[1];
    const float* bias   = (const float*)d_in[2];
    const int*   cayley = (const int*)d_in[3];
    const int*   inv    = (const int*)d_in[4];
    float* out = (float*)d_out;
    unsigned short* Wfrag = (unsigned short*)d_ws;   // 73728 bytes

    const int nrows = in_sizes[0] / 192;
    const int nstrips = nrows / 16;                  // 32768

    build_w_kernel<<<(192 * 192 + 255) / 256, 256, 0, stream>>>(kern, cayley, inv, Wfrag);

    const int nblocks = 512;                         // persistent, 2 blocks/CU
    const int nwaves  = nblocks * 8;                 // 4096 waves
    const int spw     = (nstrips + nwaves - 1) / nwaves;   // = 8
    gemm_kernel<<<nblocks, 512, 0, stream>>>(x, Wfrag, bias, out, nstrips, spw);
}

// Round 15
// 180.493 us; speedup vs baseline: 1.1146x; 1.0095x over previous
//
#include <hip/hip_runtime.h>
#include <hip/hip_bf16.h>
#include <stdint.h>

typedef __attribute__((ext_vector_type(8))) short short8;
typedef __attribute__((ext_vector_type(4))) float f32x4;
typedef __attribute__((ext_vector_type(4))) int int4v;

__device__ __forceinline__ unsigned short f2bf(float f) {
    union { float f; uint32_t u; } v; v.f = f;
    return (unsigned short)((v.u + 0x7FFFu + ((v.u >> 16) & 1u)) >> 16);
}

// Build W in MFMA-FRAGMENT order with the LINE-COALESCED k-map (R13):
//   lane (l15,lhi), elem e holds k = c*32 + (e<4 ? lhi*4+e : 16+lhi*4+(e-4))
//   Wfrag[((ct*6 + c)*64 + lane)*8 + e] = bf16( W[ct*16 + (lane&15)][k] )
// where W[j][k] = kernel[cayley[inv[k>>4], j>>4]][j&15][k&15].
// The (lane,e)->k permutation is shared by A(x) and B(W) so it cancels in MFMA.
__global__ void build_w_kernel(const float* __restrict__ kern,
                               const int* __restrict__ cayley,
                               const int* __restrict__ inv,
                               unsigned short* __restrict__ Wfrag) {
    int i = blockIdx.x * blockDim.x + threadIdx.x;   // i = ((ct*6+c)*64 + lane)*8 + e
    if (i >= 192 * 192) return;
    int e    = i & 7;
    int lane = (i >> 3) & 63;
    int fc   = i >> 9;            // ct*6 + c
    int ct   = fc / 6, c = fc - ct * 6;
    int j = ct * 16 + (lane & 15);
    int lhi = lane >> 4;
    int k = c * 32 + ((e < 4) ? (lhi * 4 + e) : (16 + lhi * 4 + (e - 4)));
    int h = j >> 4, oc = j & 15;
    int g = k >> 4, ic = k & 15;
    int cidx = cayley[inv[g] * 12 + h];
    Wfrag[i] = f2bf(kern[cidx * 256 + oc * 16 + ic]);
}

// out[n][j] = sum_k x[n][k] * W[j][k] + bias[j]
// R13 post-mortem: wall is EXPOSED ds_read LATENCY (waves idle >90%; per-strip
// ~10k cy matches 12 cts x ~870 cy of pairwise ds_read->wait->mfma). Fix (m92
// pattern): batch 12 W-fragment reads per CT-PAIR into regs, then 12 MFMAs.
// Waits 12/strip -> 6/strip, each amortized over 2x compute.
// (512,2) => 128-VGPR cap (live ~92, no spill; R2 ran 4 waves/SIMD @128).
// Keep: fragment-order LDS W (0 conflicts), line-coalesced k-map loads,
// two-batch staging, sched_barrier(0) loop bottom, swapped MFMA, plain stores.
__global__ __launch_bounds__(512, 2) void gemm_kernel(
    const float* __restrict__ x,
    const unsigned short* __restrict__ Wfrag,
    const float* __restrict__ bias,
    float* __restrict__ out, int nstrips, int spw) {
  __shared__ unsigned char lds[192 * 192 * 2];   // 73728 B, fragment order
  const int tid  = threadIdx.x;
  const int lane = tid & 63;
  const int wid  = tid >> 6;
  const int l15  = lane & 15;
  const int lhi  = lane >> 4;

  // Stage W fragments into LDS (pure linear copy, 73728 B / 512 thr = 9 x int4).
  {
    const int4v* src = (const int4v*)Wfrag;
    int4v* dst = (int4v*)lds;
    #pragma unroll
    for (int t = 0; t < 9; ++t) dst[tid + t * 512] = src[tid + t * 512];
  }
  __syncthreads();

  const int gw = blockIdx.x * 8 + wid;    // global wave id
  int strip = gw * spw;
  const int send = min(strip + spw, nstrips);

  // bias for this lane's 4 output features (j = ct*16 + lhi*4 + r)
  const f32x4 bias4 = *(const f32x4*)(bias + lhi * 4);
  // LDS fragment base for this lane: frag (ct,c) at lane*16 + (ct*6+c)*1024
  const unsigned char* wbase = lds + lane * 16;

  while (strip < send) {
    short8 abf[6];
    {
      // Lane's 16B chunk base: row l15, float offset lhi*4 within each 128B c-window.
      const float* xr = x + (size_t)(strip * 16 + l15) * 192 + lhi * 4;
      // Batch A: first 64B line of each c-window (k = c*32 + lhi*4 + 0..3)
      f32x4 fa[6];
      #pragma unroll
      for (int c = 0; c < 6; ++c) fa[c] = *(const f32x4*)(xr + c * 32);
      #pragma unroll
      for (int c = 0; c < 6; ++c)
        #pragma unroll
        for (int e = 0; e < 4; ++e) abf[c][e] = (short)f2bf(fa[c][e]);
      // Batch B: second 64B line (k = c*32 + 16 + lhi*4 + 0..3)
      f32x4 fb[6];
      #pragma unroll
      for (int c = 0; c < 6; ++c) fb[c] = *(const f32x4*)(xr + c * 32 + 16);
      #pragma unroll
      for (int c = 0; c < 6; ++c)
        #pragma unroll
        for (int e = 0; e < 4; ++e) abf[c][e + 4] = (short)f2bf(fb[c][e]);
    }

    float* obase = out + (size_t)(strip * 16 + l15) * 192 + lhi * 4;
    #pragma unroll
    for (int cp = 0; cp < 6; ++cp) {           // ct-pair: cts {2cp, 2cp+1}
      // Batch-read ALL 12 W fragments for the pair into registers first.
      short8 wf[12];
      #pragma unroll
      for (int q = 0; q < 12; ++q)
        wf[q] = *(const short8*)(wbase + (cp * 12 + q) * 1024);
      // Then 12 MFMAs (two independent acc chains interleave in the pipe).
      f32x4 acc0 = {0.f, 0.f, 0.f, 0.f};
      f32x4 acc1 = {0.f, 0.f, 0.f, 0.f};
      #pragma unroll
      for (int c = 0; c < 6; ++c) {
        acc0 = __builtin_amdgcn_mfma_f32_16x16x32_bf16(wf[c],     abf[c], acc0, 0, 0, 0);
        acc1 = __builtin_amdgcn_mfma_f32_16x16x32_bf16(wf[6 + c], abf[c], acc1, 0, 0, 0);
      }
      f32x4 r0 = {acc0[0] + bias4[0], acc0[1] + bias4[1],
                  acc0[2] + bias4[2], acc0[3] + bias4[3]};
      f32x4 r1 = {acc1[0] + bias4[0], acc1[1] + bias4[1],
                  acc1[2] + bias4[2], acc1[3] + bias4[3]};
      *(f32x4*)(obase + (2 * cp) * 16)     = r0;   // adjacent 64B halves ->
      *(f32x4*)(obase + (2 * cp + 1) * 16) = r1;   // full 128B sector, close in time
    }
    ++strip;
    // Fence: forbid hoisting next strip's loads above this point (spill source).
    __builtin_amdgcn_sched_barrier(0);
  }
}

extern "C" void kernel_launch(void* const* d_in, const int* in_sizes, int n_in,
                              void* d_out, int out_size, void* d_ws, size_t ws_size,
                              hipStream_t stream) {
    const float* x      = (const float*)d_in[0];
    const float* kern   = (const float*)d_in[1];
    const float* bias   = (const float*)d_in[2];
    const int*   cayley = (const int*)d_in[3];
    const int*   inv    = (const int*)d_in[4];
    float* out = (float*)d_out;
    unsigned short* Wfrag = (unsigned short*)d_ws;   // 73728 bytes

    const int nrows = in_sizes[0] / 192;
    const int nstrips = nrows / 16;                  // 32768

    build_w_kernel<<<(192 * 192 + 255) / 256, 256, 0, stream>>>(kern, cayley, inv, Wfrag);

    const int nblocks = 512;                         // persistent, 2 blocks/CU
    const int nwaves  = nblocks * 8;                 // 4096 waves
    const int spw     = (nstrips + nwaves - 1) / nwaves;   // = 8
    gemm_kernel<<<nblocks, 512, 0, stream>>>(x, Wfrag, bias, out, nstrips, spw);
}

// Round 16
// 176.953 us; speedup vs baseline: 1.1369x; 1.0200x over previous
//
#include <hip/hip_runtime.h>
#include <hip/hip_bf16.h>
#include <stdint.h>

typedef __attribute__((ext_vector_type(8))) short short8;
typedef __attribute__((ext_vector_type(4))) float f32x4;
typedef __attribute__((ext_vector_type(4))) int int4v;

__device__ __forceinline__ unsigned short f2bf(float f) {
    union { float f; uint32_t u; } v; v.f = f;
    return (unsigned short)((v.u + 0x7FFFu + ((v.u >> 16) & 1u)) >> 16);
}

// Build W in MFMA-FRAGMENT order with the LINE-COALESCED k-map (R13):
//   lane (l15,lhi), elem e holds k = c*32 + (e<4 ? lhi*4+e : 16+lhi*4+(e-4))
//   Wfrag[((ct*6 + c)*64 + lane)*8 + e] = bf16( W[ct*16 + (lane&15)][k] )
// where W[j][k] = kernel[cayley[inv[k>>4], j>>4]][j&15][k&15].
// The (lane,e)->k permutation is shared by A(x) and B(W) so it cancels in MFMA.
__global__ void build_w_kernel(const float* __restrict__ kern,
                               const int* __restrict__ cayley,
                               const int* __restrict__ inv,
                               unsigned short* __restrict__ Wfrag) {
    int i = blockIdx.x * blockDim.x + threadIdx.x;   // i = ((ct*6+c)*64 + lane)*8 + e
    if (i >= 192 * 192) return;
    int e    = i & 7;
    int lane = (i >> 3) & 63;
    int fc   = i >> 9;            // ct*6 + c
    int ct   = fc / 6, c = fc - ct * 6;
    int j = ct * 16 + (lane & 15);
    int lhi = lane >> 4;
    int k = c * 32 + ((e < 4) ? (lhi * 4 + e) : (16 + lhi * 4 + (e - 4)));
    int h = j >> 4, oc = j & 15;
    int g = k >> 4, ic = k & 15;
    int cidx = cayley[inv[g] * 12 + h];
    Wfrag[i] = f2bf(kern[cidx * 256 + oc * 16 + ic]);
}

// out[n][j] = sum_k x[n][k] * W[j][k] + bias[j]
// R14 post-mortem: per-CU throughput == ONE wave's serial strip latency; the
// exposed HBM wait at each strip head is never covered (R9's sched_barrier
// blocks the compiler's own 1-deep pipeline; TLP empirically doesn't cover it).
// R15: EXPLICIT 1-strip-deep prefetch. Per strip: wait+cvt (frees staging) ->
// issue next strip's 12 loads -> compute+store current strip (~2500cy covers
// ~900cy HBM). Unlike R2/R6 (spilled), body is lean: W from LDS, wf-batch 6.
// Peak live ~104 regs <= 128 cap ((512,2); ledger: cap=256/arg2).
// Keep: fragment-order LDS W (0 conflicts), line-coalesced k-map, swapped MFMA,
// plain dwordx4 stores (NT was +22us), sched_barrier(0) at loop bottom to cap
// pipelining at exactly 1 strip deep.
__global__ __launch_bounds__(512, 2) void gemm_kernel(
    const float* __restrict__ x,
    const unsigned short* __restrict__ Wfrag,
    const float* __restrict__ bias,
    float* __restrict__ out, int nstrips, int spw) {
  __shared__ unsigned char lds[192 * 192 * 2];   // 73728 B, fragment order
  const int tid  = threadIdx.x;
  const int lane = tid & 63;
  const int wid  = tid >> 6;
  const int l15  = lane & 15;
  const int lhi  = lane >> 4;

  // Stage W fragments into LDS (pure linear copy, 73728 B / 512 thr = 9 x int4).
  {
    const int4v* src = (const int4v*)Wfrag;
    int4v* dst = (int4v*)lds;
    #pragma unroll
    for (int t = 0; t < 9; ++t) dst[tid + t * 512] = src[tid + t * 512];
  }
  __syncthreads();

  const int gw = blockIdx.x * 8 + wid;    // global wave id
  int strip = gw * spw;
  const int send = min(strip + spw, nstrips);
  if (strip >= send) return;

  // bias for this lane's 4 output features (j = ct*16 + lhi*4 + r)
  const f32x4 bias4 = *(const f32x4*)(bias + lhi * 4);
  // LDS fragment base for this lane: frag (ct,c) at lane*16 + (ct*6+c)*1024
  const unsigned char* wbase = lds + lane * 16;

  // Prologue: issue strip 0's loads.
  f32x4 fa[6], fb[6];
  {
    const float* xr = x + (size_t)(strip * 16 + l15) * 192 + lhi * 4;
    #pragma unroll
    for (int c = 0; c < 6; ++c) {
      fa[c] = *(const f32x4*)(xr + c * 32);        // k = c*32 + lhi*4 + 0..3
      fb[c] = *(const f32x4*)(xr + c * 32 + 16);   // k = c*32 + 16 + lhi*4 + 0..3
    }
  }

  while (strip < send) {
    // Wait for this strip's loads; convert (frees fa/fb for reuse).
    short8 abf[6];
    #pragma unroll
    for (int c = 0; c < 6; ++c) {
      short8 v;
      #pragma unroll
      for (int e = 0; e < 4; ++e) {
        v[e]     = (short)f2bf(fa[c][e]);
        v[e + 4] = (short)f2bf(fb[c][e]);
      }
      abf[c] = v;
    }

    // Issue NEXT strip's loads now; ~2500cy of compute below covers the latency.
    const int nxt = strip + 1;
    if (nxt < send) {
      const float* xr = x + (size_t)(nxt * 16 + l15) * 192 + lhi * 4;
      #pragma unroll
      for (int c = 0; c < 6; ++c) {
        fa[c] = *(const f32x4*)(xr + c * 32);
        fb[c] = *(const f32x4*)(xr + c * 32 + 16);
      }
    }

    float* obase = out + (size_t)(strip * 16 + l15) * 192 + lhi * 4;
    #pragma unroll
    for (int cp = 0; cp < 6; ++cp) {           // ct-pair: cts {2cp, 2cp+1}
      short8 wf0[6], wf1[6];
      #pragma unroll
      for (int c = 0; c < 6; ++c) wf0[c] = *(const short8*)(wbase + (cp * 12 + c) * 1024);
      f32x4 acc0 = {0.f, 0.f, 0.f, 0.f};
      #pragma unroll
      for (int c = 0; c < 6; ++c)
        acc0 = __builtin_amdgcn_mfma_f32_16x16x32_bf16(wf0[c], abf[c], acc0, 0, 0, 0);
      #pragma unroll
      for (int c = 0; c < 6; ++c) wf1[c] = *(const short8*)(wbase + (cp * 12 + 6 + c) * 1024);
      f32x4 acc1 = {0.f, 0.f, 0.f, 0.f};
      #pragma unroll
      for (int c = 0; c < 6; ++c)
        acc1 = __builtin_amdgcn_mfma_f32_16x16x32_bf16(wf1[c], abf[c], acc1, 0, 0, 0);
      f32x4 r0 = {acc0[0] + bias4[0], acc0[1] + bias4[1],
                  acc0[2] + bias4[2], acc0[3] + bias4[3]};
      f32x4 r1 = {acc1[0] + bias4[0], acc1[1] + bias4[1],
                  acc1[2] + bias4[2], acc1[3] + bias4[3]};
      *(f32x4*)(obase + (2 * cp) * 16)     = r0;
      *(f32x4*)(obase + (2 * cp + 1) * 16) = r1;
    }
    strip = nxt;
    // Cap pipelining at exactly 1 strip deep (no compiler over-hoisting).
    __builtin_amdgcn_sched_barrier(0);
  }
}

extern "C" void kernel_launch(void* const* d_in, const int* in_sizes, int n_in,
                              void* d_out, int out_size, void* d_ws, size_t ws_size,
                              hipStream_t stream) {
    const float* x      = (const float*)d_in[0];
    const float* kern   = (const float*)d_in[1];
    const float* bias   = (const float*)d_in[2];
    const int*   cayley = (const int*)d_in[3];
    const int*   inv    = (const int*)d_in[4];
    float* out = (float*)d_out;
    unsigned short* Wfrag = (unsigned short*)d_ws;   // 73728 bytes

    const int nrows = in_sizes[0] / 192;
    const int nstrips = nrows / 16;                  // 32768

    build_w_kernel<<<(192 * 192 + 255) / 256, 256, 0, stream>>>(kern, cayley, inv, Wfrag);

    const int nblocks = 512;                         // persistent, 2 blocks/CU
    const int nwaves  = nblocks * 8;                 // 4096 waves
    const int spw     = (nstrips + nwaves - 1) / nwaves;   // = 8
    gemm_kernel<<<nblocks, 512, 0, stream>>>(x, Wfrag, bias, out, nstrips, spw);
}